// Round 1
// baseline (163.801 us; speedup 1.0000x reference)
//
#include <hip/hip_runtime.h>

#define N 8192
#define KD 128
#define NCLS 10
#define NCH 8
#define CHUNK (N / NCH) /* 1024 */

typedef __attribute__((ext_vector_type(8))) short short8;
typedef __attribute__((ext_vector_type(4))) float floatx4;

__device__ __forceinline__ unsigned short f2bf(float x) {
    unsigned u = __float_as_uint(x);
    u += 0x7fffu + ((u >> 16) & 1u);   // round-to-nearest-even
    return (unsigned short)(u >> 16);
}

// ---------------- k_init: class counts + zero S + zero acc ----------------
__global__ void k_init(const int* __restrict__ tgt, int* __restrict__ cnt,
                       float* __restrict__ acc, float* __restrict__ S) {
    int t = threadIdx.x;
    int local[NCLS];
#pragma unroll
    for (int c = 0; c < NCLS; ++c) local[c] = 0;
    for (int i = t; i < N; i += 256) {
        int c = tgt[i];
#pragma unroll
        for (int cc = 0; cc < NCLS; ++cc) local[cc] += (cc == c) ? 1 : 0;
    }
    __shared__ int red[256];
    for (int cc = 0; cc < NCLS; ++cc) {
        red[t] = local[cc];
        __syncthreads();
        for (int off = 128; off > 0; off >>= 1) {
            if (t < off) red[t] += red[t + off];
            __syncthreads();
        }
        if (t == 0) cnt[cc] = red[0];
        __syncthreads();
    }
    for (int i = t; i < NCLS * KD; i += 256) S[i] = 0.f;
    if (t == 0) acc[0] = 0.f;
}

// ---------------- k_csum: class feature sums S[c][k] ----------------
__global__ void k_csum(const float* __restrict__ F, const int* __restrict__ tgt,
                       float* __restrict__ S) {
    int t = threadIdx.x;
    int k = t & 127;
    int h = t >> 7;                      // which 128-row half
    int row0 = blockIdx.x * 256 + h * 128;
    float local[NCLS];
#pragma unroll
    for (int c = 0; c < NCLS; ++c) local[c] = 0.f;
    for (int ii = 0; ii < 128; ++ii) {
        int i = row0 + ii;
        float v = F[i * KD + k];
        int c = tgt[i];
#pragma unroll
        for (int cc = 0; cc < NCLS; ++cc) local[cc] += (cc == c) ? v : 0.f;
    }
    __shared__ float red[2][NCLS][KD];   // 10 KiB
#pragma unroll
    for (int cc = 0; cc < NCLS; ++cc) red[h][cc][k] = local[cc];
    __syncthreads();
    if (h == 0) {
#pragma unroll
        for (int cc = 0; cc < NCLS; ++cc)
            atomicAdd(&S[cc * KD + k], red[0][cc][k] + red[1][cc][k]);
    }
}

// ---------------- k_row: posdot + bf16 conversion (A scaled x10) ----------------
__global__ void k_row(const float* __restrict__ F, const int* __restrict__ tgt,
                      const float* __restrict__ S, float* __restrict__ posdot,
                      unsigned short* __restrict__ A10, unsigned short* __restrict__ B1) {
    int row = blockIdx.x * 4 + (threadIdx.x >> 6);
    int lane = threadIdx.x & 63;
    float2 fv = *(const float2*)(F + row * KD + lane * 2);
    int c = tgt[row];
    float2 sv = *(const float2*)(S + c * KD + lane * 2);
    float dS = fv.x * sv.x + fv.y * sv.y;
    float sq = fv.x * fv.x + fv.y * fv.y;
#pragma unroll
    for (int off = 32; off >= 1; off >>= 1) {
        dS += __shfl_xor(dS, off);
        sq += __shfl_xor(sq, off);
    }
    if (lane == 0) posdot[row] = dS - sq;   // sum over positives of raw dot
    ushort2 av, bv;
    av.x = f2bf(10.f * fv.x); av.y = f2bf(10.f * fv.y);
    bv.x = f2bf(fv.x);        bv.y = f2bf(fv.y);
    *(ushort2*)(A10 + row * KD + lane * 2) = av;
    *(ushort2*)(B1 + row * KD + lane * 2) = bv;
}

// ---------------- k_pair: streaming pairwise max + sum-exp ----------------
// Grid: (N/128 row blocks, NCH chunks). Block 256 = 4 waves of 32 rows each.
// Wave tile: 32 rows x 128 cols per j-step (2x8 MFMA 16x16x32 tiles, K=128).
__global__ __launch_bounds__(256, 2) void k_pair(const unsigned short* __restrict__ A10,
                                                 const unsigned short* __restrict__ B1,
                                                 float* __restrict__ pm,
                                                 float* __restrict__ ps) {
    int bx = blockIdx.x, ch = blockIdx.y;
    int tid = threadIdx.x;
    int wid = tid >> 6, lane = tid & 63;
    int quad = lane >> 4, l16 = lane & 15;
    int wg_row0 = bx * 128;
    int row0 = wg_row0 + wid * 32;

    // A fragments resident for the whole sweep: A[m=l16][k=quad*8+j]
    short8 af[2][4];
#pragma unroll
    for (int ti = 0; ti < 2; ++ti)
#pragma unroll
        for (int ks = 0; ks < 4; ++ks) {
            int r = row0 + ti * 16 + l16;
            af[ti][ks] = *(const short8*)(A10 + r * KD + ks * 32 + quad * 8);
        }

    float m[8], s[8];                    // slot = ti*4 + r  (8 rows/lane)
#pragma unroll
    for (int i = 0; i < 8; ++i) { m[i] = -INFINITY; s[i] = 0.f; }

    int ccol0 = ch * CHUNK;
    for (int jj = 0; jj < CHUNK / 128; ++jj) {
        int col0 = ccol0 + jj * 128;
        floatx4 acc[2][8];
#pragma unroll
        for (int ti = 0; ti < 2; ++ti)
#pragma unroll
            for (int tj = 0; tj < 8; ++tj)
                acc[ti][tj] = (floatx4){0.f, 0.f, 0.f, 0.f};

#pragma unroll
        for (int ks = 0; ks < 4; ++ks) {
            short8 bf[8];                // B[k=quad*8+j][n=l16] = row (col) of B1
#pragma unroll
            for (int tj = 0; tj < 8; ++tj) {
                int cidx = col0 + tj * 16 + l16;
                bf[tj] = *(const short8*)(B1 + cidx * KD + ks * 32 + quad * 8);
            }
#pragma unroll
            for (int ti = 0; ti < 2; ++ti)
#pragma unroll
                for (int tj = 0; tj < 8; ++tj)
                    acc[ti][tj] = __builtin_amdgcn_mfma_f32_16x16x32_bf16(
                        af[ti][ks], bf[tj], acc[ti][tj], 0, 0, 0);
        }

        bool has_diag = (col0 == wg_row0);   // wave-uniform
#pragma unroll
        for (int ti = 0; ti < 2; ++ti)
#pragma unroll
            for (int r = 0; r < 4; ++r) {
                int slot = ti * 4 + r;
                float v[8];
#pragma unroll
                for (int tj = 0; tj < 8; ++tj) v[tj] = acc[ti][tj][r];
                float mb = fmaxf(fmaxf(fmaxf(v[0], v[1]), fmaxf(v[2], v[3])),
                                 fmaxf(fmaxf(v[4], v[5]), fmaxf(v[6], v[7])));
                float e[8];
#pragma unroll
                for (int tj = 0; tj < 8; ++tj) e[tj] = __expf(v[tj] - mb);
                if (has_diag) {
                    // diag element: row - col0 = wid*32 + ti*16 + quad*4 + r
                    if (l16 == quad * 4 + r) e[wid * 2 + ti] = 0.f;  // max keeps diag, sum drops it
                }
                float sb = ((e[0] + e[1]) + (e[2] + e[3])) + ((e[4] + e[5]) + (e[6] + e[7]));
                float mn = fmaxf(m[slot], mb);
                s[slot] = s[slot] * __expf(m[slot] - mn) + sb * __expf(mb - mn);
                m[slot] = mn;
            }
    }

    // merge across the 16 lanes of each quad (cols), then lane l16==0 writes
#pragma unroll
    for (int slot = 0; slot < 8; ++slot) {
        float mm = m[slot], ss = s[slot];
#pragma unroll
        for (int off = 1; off < 16; off <<= 1) {
            float mo = __shfl_xor(mm, off);
            float so = __shfl_xor(ss, off);
            float mn = fmaxf(mm, mo);
            ss = ss * __expf(mm - mn) + so * __expf(mo - mn);
            mm = mn;
        }
        if (l16 == 0) {
            int ti = slot >> 2, r = slot & 3;
            int row = row0 + ti * 16 + quad * 4 + r;
            pm[ch * N + row] = mm;
            ps[ch * N + row] = ss;
        }
    }
}

// ---------------- k_final: merge chunks, per-row term, reduce ----------------
__global__ void k_final(const float* __restrict__ pm, const float* __restrict__ ps,
                        const float* __restrict__ posdot, const int* __restrict__ tgt,
                        const int* __restrict__ cnt, float* __restrict__ acc) {
    int i = blockIdx.x * 256 + threadIdx.x;
    float mm = -INFINITY, ss = 0.f;
#pragma unroll
    for (int c = 0; c < NCH; ++c) {
        float mo = pm[c * N + i];
        float so = ps[c * N + i];
        float mn = fmaxf(mm, mo);
        ss = ss * __expf(mm - mn) + so * __expf(mo - mn);
        mm = mn;
    }
    float logden = __logf(ss + 1e-20f);
    float np = (float)(cnt[tgt[i]] - 1);
    float mlp = (posdot[i] * 10.f - np * (mm + logden)) / (np + 1e-20f);
#pragma unroll
    for (int off = 32; off >= 1; off >>= 1) mlp += __shfl_xor(mlp, off);
    __shared__ float wsum[4];
    int lane = threadIdx.x & 63, w = threadIdx.x >> 6;
    if (lane == 0) wsum[w] = mlp;
    __syncthreads();
    if (threadIdx.x == 0)
        atomicAdd(acc, (wsum[0] + wsum[1]) + (wsum[2] + wsum[3]));
}

// ---------------- k_out: final 3 scalars ----------------
__global__ void k_out(const float* __restrict__ acc, const int* __restrict__ cnt,
                      float* __restrict__ out) {
    if (threadIdx.x == 0) {
        double sp = 0.0, sn = 0.0;
        for (int c = 0; c < NCLS; ++c) {
            double n = (double)cnt[c];
            sp += n * (n - 1.0);
            sn += n * ((double)N - n);
        }
        out[0] = (float)(-(0.1 / 0.07) * ((double)acc[0] / (double)N));
        out[1] = (float)(sp / (double)N);
        out[2] = (float)(sn / (double)N);
    }
}

extern "C" void kernel_launch(void* const* d_in, const int* in_sizes, int n_in,
                              void* d_out, int out_size, void* d_ws, size_t ws_size,
                              hipStream_t stream) {
    const float* F = (const float*)d_in[0];
    const int* tgt = (const int*)d_in[1];
    float* out = (float*)d_out;
    char* ws = (char*)d_ws;

    int* cnt = (int*)(ws);                        // 64 B
    float* acc = (float*)(ws + 64);               // 64 B
    float* S = (float*)(ws + 128);                // 5120 B
    float* posdot = (float*)(ws + 8192);          // 32 KiB
    float* pm = (float*)(ws + 40960);             // 256 KiB
    float* ps = (float*)(ws + 40960 + NCH * N * 4);
    unsigned short* A10 = (unsigned short*)(ws + (1u << 20));      // 2 MiB (x10-scaled bf16)
    unsigned short* B1 = (unsigned short*)(ws + 3u * (1u << 20));  // 2 MiB (bf16)

    k_init<<<1, 256, 0, stream>>>(tgt, cnt, acc, S);
    k_csum<<<N / 256, 256, 0, stream>>>(F, tgt, S);
    k_row<<<N / 4, 256, 0, stream>>>(F, tgt, S, posdot, A10, B1);
    k_pair<<<dim3(N / 128, NCH), 256, 0, stream>>>(A10, B1, pm, ps);
    k_final<<<N / 256, 256, 0, stream>>>(pm, ps, posdot, tgt, cnt, acc);
    k_out<<<1, 64, 0, stream>>>(acc, cnt, out);
}